// Round 2
// 391.671 us; speedup vs baseline: 1.0492x; 1.0492x over previous
//
#include <hip/hip_runtime.h>
#include <cstddef>
#include <cstdint>

// Dims fixed by the reference: input [T=128, B=256, D1=1024] fp32,
// weight [D2=512, D1=1024] fp32. Outputs spk/V/I each [T,B,D2] fp32 concat.
#define TT 128
#define BB 256
#define D1 1024
#define D2 512
#define SS (BB * D2)      // 131072 elems per timestep slice
#define MM (127 * BB)     // 32512 GEMM rows

#define ALPHA 0.8187307530779818f
#define BETA  0.9048374180359595f

typedef _Float16 half8 __attribute__((ext_vector_type(8)));
typedef float floatx16 __attribute__((ext_vector_type(16)));

// ---------------------------------------------------------------------------
// convert_w: fp32 W -> f16 hi + f16 lo*2048 planes, PRE-SWIZZLED into MFMA
// fragment order so the GEMM can stage W with global_load_lds_dwordx4 into a
// linear LDS buffer and read fragments with perfectly stride-1 ds_read_b128.
//
// Plane layout (halfs): idx = ((kt*4 + nB)*8 + ch)*512 + l*8 + e
//   kt in [0,32): K-tile of 32; nB in [0,4): 128-row block of W (= C col blk)
//   row = nB*128 + (ch&3)*32 + (l&31); k = kt*32 + (ch>>2)*16 + (l>>5)*8 + e
// This is exactly the per-lane content of the 32x32x16 B-fragment.
// ---------------------------------------------------------------------------
__global__ __launch_bounds__(256) void convert_w(const float* __restrict__ W,
                                                 _Float16* __restrict__ Whi,
                                                 _Float16* __restrict__ Wlo) {
    const int T = blockIdx.x * 256 + threadIdx.x;   // 65536 threads, 8 halfs each
    const int l = T & 63;
    const int ch = (T >> 6) & 7;
    const int nB = (T >> 9) & 3;
    const int kt = T >> 11;
    const int row = nB * 128 + (ch & 3) * 32 + (l & 31);
    const int k = kt * 32 + (ch >> 2) * 16 + (l >> 5) * 8;
    const float* src = W + (size_t)row * D1 + k;
    float4 w0 = *(const float4*)src;
    float4 w1 = *(const float4*)(src + 4);
    float f[8] = {w0.x, w0.y, w0.z, w0.w, w1.x, w1.y, w1.z, w1.w};
    half8 hi, lo;
#pragma unroll
    for (int j = 0; j < 8; ++j) {
        _Float16 h = (_Float16)f[j];
        hi[j] = h;
        lo[j] = (_Float16)((f[j] - (float)h) * 2048.0f);
    }
    *(half8*)(Whi + (size_t)T * 8) = hi;
    *(half8*)(Wlo + (size_t)T * 8) = lo;
}

// ---------------------------------------------------------------------------
// Split-f16 MFMA GEMM, counted-vmcnt raw-barrier pipeline (T3/T4 + T5).
// C = (hiA*hiB) + 2^-11 * (hiA*loB + loA*hiB); lo terms pre-scaled by 2048.
//
// Tile BM=128 x BN=128 x BK=32, 512 threads (8 waves, 2M x 4N), wave-tile
// 64x32 as 2x1 of mfma_f32_32x32x16_f16 (acc = 2x16x2 = 64 regs/thread).
// LDS: 2 buffers x 4 planes (Ah,Al,Wh,Wl) x 8KB = 64 KB, chunked layout:
// chunk ch (1 KB) = one wave-fragment; every ds_read/ds_write is base+lane*16
// (stride-1, zero bank conflicts). W staged by global_load_lds from the
// pre-swizzled planes (linear dest = fragment order). A reg-staged (fp32 ->
// hi/lo conversion) with depth-2 prefetch.
//
// Register rotation (THE round-1 bug, now fixed): prologue leaves ra=tile0
// (already staged), rb=tile1 (in flight). BODY(jj) stages tile jj+1 from the
// CURRENT regs (C0,C1) and prefetches tile jj+2 into the FREE regs (N0,N1):
// even jj: C=rb, N=ra;  odd jj: C=ra, N=rb.
//
// Main loop per K-tile j (buf c = j&1):
//   top:  issue W(j+1) gload_lds -> buf c^1 (2 instrs); issue A(j+2) -> regs
//   mid:  convert A(j+1) regs -> ds_write buf c^1
//         MFMA tile j from buf c (setprio-wrapped)
//   end:  s_waitcnt vmcnt(2) (W(j+1) landed, A(j+2) still in flight!)
//         + lgkmcnt(0), raw s_barrier.
// ---------------------------------------------------------------------------
#define GLOAD16(gp, lp)                                                        \
    __builtin_amdgcn_global_load_lds(                                          \
        (const __attribute__((address_space(1))) void*)(gp),                   \
        (__attribute__((address_space(3))) void*)(lp), 16, 0, 0)

__global__ __launch_bounds__(512, 2) void gemm_mfma(const float* __restrict__ A,
                                                    const _Float16* __restrict__ Whi,
                                                    const _Float16* __restrict__ Wlo,
                                                    float* __restrict__ C) {
    // [buf][plane: 0=Ah 1=Al 2=Wh 3=Wl][8 chunks * 512 halfs]
    __shared__ _Float16 lds[2][4][4096];

    const int tid = threadIdx.x;
    const int lane = tid & 63;
    const int w = tid >> 6;             // wave 0..7
    const int wm = w >> 2;              // M half: rows wm*64 + mb*32
    const int wn = w & 3;               // N quarter: cols wn*32
    const int bm = blockIdx.x * 128;
    const int nB = blockIdx.y;          // 128-col block of C
    const int bn = nB * 128;
    const int m_ = lane & 31;
    const int q = lane >> 5;

    // ---- A staging map: thread -> (row r0, k-octet o_) ----
    const int o_ = tid & 3;
    const int r0 = tid >> 2;            // 0..127, one row per thread
    const int chA = ((o_ >> 1) << 2) + (r0 >> 5);         // kstep*4 + row>>5
    const int sA = chA * 512 + ((o_ & 1) * 32 + (r0 & 31)) * 8;
    const float* Ab0 = A + (size_t)(bm + r0) * D1 + o_ * 8;

    // ---- W gload_lds: wave w moves chunk w of each plane (1 KB/instr) ----
    const _Float16* WsrcH = Whi + (size_t)nB * 4096 + w * 512 + lane * 8;
    const _Float16* WsrcL = Wlo + (size_t)nB * 4096 + w * 512 + lane * 8;

    // ---- fragment read offsets (halfs), + KS*2048 per k-step ----
    const int fA0 = (wm * 2 + 0) * 512 + lane * 8;
    const int fA1 = (wm * 2 + 1) * 512 + lane * 8;
    const int fB = wn * 512 + lane * 8;

    floatx16 accm[2], accl[2];
    accm[0] = (floatx16)0.0f; accm[1] = (floatx16)0.0f;
    accl[0] = (floatx16)0.0f; accl[1] = (floatx16)0.0f;

    float4 ra0, ra1;   // A prefetch set A
    float4 rb0, rb1;   // A prefetch set B

#define STAGE_A(BUF, F0, F1)                                                   \
    {                                                                          \
        float fv[8] = {F0.x, F0.y, F0.z, F0.w, F1.x, F1.y, F1.z, F1.w};        \
        half8 hh, ll;                                                          \
        _Pragma("unroll")                                                      \
        for (int u = 0; u < 8; ++u) {                                          \
            _Float16 hv = (_Float16)fv[u];                                     \
            hh[u] = hv;                                                        \
            ll[u] = (_Float16)((fv[u] - (float)hv) * 2048.0f);                 \
        }                                                                      \
        *(half8*)&lds[BUF][0][sA] = hh;                                        \
        *(half8*)&lds[BUF][1][sA] = ll;                                        \
    }

#define MFMA6(BUF, KS)                                                         \
    {                                                                          \
        const half8 ah0 = *(const half8*)&lds[BUF][0][fA0 + (KS)*2048];        \
        const half8 ah1 = *(const half8*)&lds[BUF][0][fA1 + (KS)*2048];        \
        const half8 al0 = *(const half8*)&lds[BUF][1][fA0 + (KS)*2048];        \
        const half8 al1 = *(const half8*)&lds[BUF][1][fA1 + (KS)*2048];        \
        const half8 bh = *(const half8*)&lds[BUF][2][fB + (KS)*2048];          \
        const half8 bl = *(const half8*)&lds[BUF][3][fB + (KS)*2048];          \
        accm[0] = __builtin_amdgcn_mfma_f32_32x32x16_f16(ah0, bh, accm[0], 0, 0, 0); \
        accl[0] = __builtin_amdgcn_mfma_f32_32x32x16_f16(ah0, bl, accl[0], 0, 0, 0); \
        accl[0] = __builtin_amdgcn_mfma_f32_32x32x16_f16(al0, bh, accl[0], 0, 0, 0); \
        accm[1] = __builtin_amdgcn_mfma_f32_32x32x16_f16(ah1, bh, accm[1], 0, 0, 0); \
        accl[1] = __builtin_amdgcn_mfma_f32_32x32x16_f16(ah1, bl, accl[1], 0, 0, 0); \
        accl[1] = __builtin_amdgcn_mfma_f32_32x32x16_f16(al1, bh, accl[1], 0, 0, 0); \
    }

#define BODY(JT, BUF, C0, C1, N0, N1, PREF_A, VMN)                             \
    {                                                                          \
        asm volatile("" ::: "memory"); /* post-barrier fence */                \
        GLOAD16(WsrcH + (size_t)((JT) + 1) * 16384, &lds[(BUF) ^ 1][2][w * 512]); \
        GLOAD16(WsrcL + (size_t)((JT) + 1) * 16384, &lds[(BUF) ^ 1][3][w * 512]); \
        __builtin_amdgcn_sched_barrier(0); /* keep gloads before A loads */    \
        if (PREF_A) {                                                          \
            const int kf = ((JT) + 2) * 32;                                    \
            N0 = *(const float4*)(Ab0 + kf);                                   \
            N1 = *(const float4*)(Ab0 + kf + 4);                               \
        }                                                                      \
        STAGE_A((BUF) ^ 1, C0, C1);                                            \
        __builtin_amdgcn_s_setprio(1);                                         \
        MFMA6(BUF, 0);                                                         \
        __builtin_amdgcn_s_setprio(0);                                         \
        __builtin_amdgcn_s_setprio(1);                                         \
        MFMA6(BUF, 1);                                                         \
        __builtin_amdgcn_s_setprio(0);                                         \
        asm volatile("s_waitcnt vmcnt(" #VMN ") lgkmcnt(0)" ::: "memory");     \
        __builtin_amdgcn_s_barrier();                                          \
    }

    // ---- prologue: tile0 staged (from ra), tile1 A-regs (rb) in flight ----
    GLOAD16(WsrcH, &lds[0][2][w * 512]);
    GLOAD16(WsrcL, &lds[0][3][w * 512]);
    __builtin_amdgcn_sched_barrier(0);
    ra0 = *(const float4*)(Ab0);
    ra1 = *(const float4*)(Ab0 + 4);
    rb0 = *(const float4*)(Ab0 + 32);
    rb1 = *(const float4*)(Ab0 + 36);
    STAGE_A(0, ra0, ra1);
    asm volatile("s_waitcnt vmcnt(2) lgkmcnt(0)" ::: "memory"); // W0 landed; A1 flies
    __builtin_amdgcn_s_barrier();

    // ---- main loop: tiles 0..29 in buf-parity pairs ----
    // even jj: stage A(jj+1) from rb, prefetch A(jj+2) into ra; odd jj: swap.
    for (int jj = 0; jj < 30; jj += 2) {
        BODY(jj, 0, rb0, rb1, ra0, ra1, 1, 2)
        BODY(jj + 1, 1, ra0, ra1, rb0, rb1, 1, 2)
    }
    // tile 30: stage A(31) from rb, prefetch W(31) only, drain everything
    BODY(30, 0, rb0, rb1, ra0, ra1, 0, 0)
    // tile 31: compute only
    asm volatile("" ::: "memory");
    __builtin_amdgcn_s_setprio(1);
    MFMA6(1, 0);
    __builtin_amdgcn_s_setprio(0);
    __builtin_amdgcn_s_setprio(1);
    MFMA6(1, 1);
    __builtin_amdgcn_s_setprio(0);

#undef BODY
#undef MFMA6
#undef STAGE_A

    // ---- epilogue: C/D layout col=lane&31, row=(reg&3)+8*(reg>>2)+4*q ----
    const int n = bn + wn * 32 + m_;
#pragma unroll
    for (int mb = 0; mb < 2; ++mb) {
#pragma unroll
        for (int reg = 0; reg < 16; ++reg) {
            const int row = (reg & 3) + 8 * (reg >> 2) + 4 * q;
            const int m = bm + wm * 64 + mb * 32 + row;
            C[(size_t)m * D2 + n] = accm[mb][reg] + accl[mb][reg] * (1.0f / 2048.0f);
        }
    }
}

// ---------------------------------------------------------------------------
// Scan: sequential in t, parallel over (b,d2). Manual 4-deep load pipeline.
// ---------------------------------------------------------------------------
__global__ __launch_bounds__(256) void scan_kernel(float* __restrict__ out) {
    const int j = blockIdx.x * 256 + threadIdx.x;
    float* spk = out;
    float* V = out + TT * SS;
    float* I = out + 2 * TT * SS;

    spk[j] = 0.0f;
    V[j] = 0.0f;
    I[j] = 0.0f;

    float syn = 0.0f, mem = 0.0f;

#define STEP(tt, cc)                                     \
    {                                                    \
        const float reset = (mem > 1.0f) ? 1.0f : 0.0f;  \
        syn = ALPHA * syn + (cc);                        \
        mem = (BETA * mem + syn) * (1.0f - reset);       \
        const int idx = (tt) * SS + j;                   \
        spk[idx] = (mem > 1.0f) ? 1.0f : 0.0f;           \
        V[idx] = mem;                                    \
        I[idx] = syn;                                    \
    }

    float c0 = I[1 * SS + j];
    float c1 = I[2 * SS + j];
    float c2 = I[3 * SS + j];
    float c3 = I[4 * SS + j];

    int t = 1;
    for (; t <= 117; t += 4) {
        const float n0 = I[(t + 4) * SS + j];
        const float n1 = I[(t + 5) * SS + j];
        const float n2 = I[(t + 6) * SS + j];
        const float n3 = I[(t + 7) * SS + j];
        STEP(t + 0, c0);
        STEP(t + 1, c1);
        STEP(t + 2, c2);
        STEP(t + 3, c3);
        c0 = n0; c1 = n1; c2 = n2; c3 = n3;
    }
    {
        const float n0 = I[125 * SS + j];
        const float n1 = I[126 * SS + j];
        const float n2 = I[127 * SS + j];
        STEP(121, c0);
        STEP(122, c1);
        STEP(123, c2);
        STEP(124, c3);
        STEP(125, n0);
        STEP(126, n1);
        STEP(127, n2);
    }
#undef STEP
}

extern "C" void kernel_launch(void* const* d_in, const int* in_sizes, int n_in,
                              void* d_out, int out_size, void* d_ws, size_t ws_size,
                              hipStream_t stream) {
    const float* input = (const float*)d_in[0];   // [128,256,1024]
    const float* weight = (const float*)d_in[1];  // [512,1024]
    float* out = (float*)d_out;

    // f16 hi/lo W planes (pre-swizzled) stashed in spk slices 1..4 (2 MB);
    // gemm reads them, scan overwrites them afterwards.
    _Float16* Whi = (_Float16*)(out + SS);
    _Float16* Wlo = Whi + (size_t)D2 * D1;

    // cur for scan step t at I-region slice t (shift by one slice)
    float* Cdst = out + (size_t)2 * TT * SS + SS;

    convert_w<<<dim3((D2 * D1 / 8) / 256), dim3(256), 0, stream>>>(weight, Whi, Wlo);
    gemm_mfma<<<dim3(MM / 128, D2 / 128), dim3(512), 0, stream>>>(input, Whi, Wlo, Cdst);
    scan_kernel<<<dim3(SS / 256), dim3(256), 0, stream>>>(out);
}

// Round 3
// 387.364 us; speedup vs baseline: 1.0609x; 1.0111x over previous
//
#include <hip/hip_runtime.h>
#include <cstddef>
#include <cstdint>

// Dims fixed by the reference: input [T=128, B=256, D1=1024] fp32,
// weight [D2=512, D1=1024] fp32. Outputs spk/V/I each [T,B,D2] fp32 concat.
#define TT 128
#define BB 256
#define D1 1024
#define D2 512
#define SS (BB * D2)      // 131072 elems per timestep slice
#define MM (127 * BB)     // 32512 GEMM rows

#define ALPHA 0.8187307530779818f
#define BETA  0.9048374180359595f

typedef _Float16 half8 __attribute__((ext_vector_type(8)));
typedef float floatx16 __attribute__((ext_vector_type(16)));

// ---------------------------------------------------------------------------
// convert_w: fp32 W -> f16 hi + f16 lo*2048 planes, PRE-SWIZZLED into MFMA
// fragment order for the BN=256 GEMM tile. Linear gload_lds dest = fragment
// order; all GEMM ds ops are base + lane*16 (minimal 8-way b128 aliasing).
//
// Plane layout (halfs): idx = ((kt*2 + nB)*16 + ch)*512 + l*8 + e
//   kt in [0,32): K-tile of 32; nB in [0,2): 256-col block of C
//   ch = kstep*8 + cb (cb = 32-col sub-block 0..7); l = q*32 + (row&31)
//   row = nB*256 + (ch&7)*32 + (l&31); k = kt*32 + (ch>>3)*16 + (l>>5)*8 + e
// This is exactly the per-lane content of the 32x32x16 B-fragment.
// ---------------------------------------------------------------------------
__global__ __launch_bounds__(256) void convert_w(const float* __restrict__ W,
                                                 _Float16* __restrict__ Whi,
                                                 _Float16* __restrict__ Wlo) {
    const int T = blockIdx.x * 256 + threadIdx.x;   // 65536 threads, 8 halfs each
    const int l = T & 63;
    const int ch = (T >> 6) & 15;
    const int nB = (T >> 10) & 1;
    const int kt = T >> 11;
    const int row = nB * 256 + (ch & 7) * 32 + (l & 31);
    const int k = kt * 32 + (ch >> 3) * 16 + (l >> 5) * 8;
    const float* src = W + (size_t)row * D1 + k;
    float4 w0 = *(const float4*)src;
    float4 w1 = *(const float4*)(src + 4);
    float f[8] = {w0.x, w0.y, w0.z, w0.w, w1.x, w1.y, w1.z, w1.w};
    half8 hi, lo;
#pragma unroll
    for (int j = 0; j < 8; ++j) {
        _Float16 h = (_Float16)f[j];
        hi[j] = h;
        lo[j] = (_Float16)((f[j] - (float)h) * 2048.0f);
    }
    *(half8*)(Whi + (size_t)T * 8) = hi;
    *(half8*)(Wlo + (size_t)T * 8) = lo;
}

// ---------------------------------------------------------------------------
// Split-f16 MFMA GEMM, counted-vmcnt raw-barrier pipeline (T3/T4 + T5).
// C = (hiA*hiB) + 2^-11 * (hiA*loB + loA*hiB); lo terms pre-scaled by 2048.
//
// Round-3 geometry change (LDS-BW driven): BM=128 x BN=256 x BK=32,
// 512 threads (8 waves, 2M x 4N), wave-tile 64x64 as 2x2 of
// mfma_f32_32x32x16_f16 (acc = 128 regs/thread). Per k-step a wave reads
// 8 x ds_read_b128 (8 KB) and issues 12 MFMAs: ~933 B LDS traffic per
// 8-cy MFMA CU-slot (vs 1365 B at 64x32), under the ~1 KB/slot LDS budget
// that capped MfmaUtil at 33%.
//
// LDS: 2 buf x 48 KB = 96 KB (1 block/CU). Per buffer (halfs):
//   Ah @0 (8 chunks), Al @4096, Wh @8192 (16 chunks), Wl @16384.
// chunk = 512 halfs = one 32x16 fragment in lane-major order.
//
// Rotation (validated in round 2): prologue leaves ra=tile0 (staged),
// rb=tile1 (in flight). BODY(jj) stages tile jj+1 from C-regs, prefetches
// tile jj+2 into N-regs: even jj C=rb,N=ra; odd jj C=ra,N=rb.
// Steady-state vmcnt(2): 4 W-gloads (j+1) drained, 2 A-loads (j+2) kept.
// Grid (2, 254): blockIdx.x = nB so the two A-sharing twins dispatch
// adjacently -> second A read hits L2/L3.
// ---------------------------------------------------------------------------
#define AHo 0
#define ALo 4096
#define WHo 8192
#define WLo 16384
#define BUFSZ 24576

#define GLOAD16(gp, lp)                                                        \
    __builtin_amdgcn_global_load_lds(                                          \
        (const __attribute__((address_space(1))) void*)(gp),                   \
        (__attribute__((address_space(3))) void*)(lp), 16, 0, 0)

__global__ __launch_bounds__(512, 2) void gemm_mfma(const float* __restrict__ A,
                                                    const _Float16* __restrict__ Whi,
                                                    const _Float16* __restrict__ Wlo,
                                                    float* __restrict__ C) {
    __shared__ _Float16 lds[2][BUFSZ];

    const int tid = threadIdx.x;
    const int lane = tid & 63;
    const int w = tid >> 6;             // wave 0..7
    const int wm = w >> 2;              // M half: rows wm*64 + mb*32
    const int wn = w & 3;               // N quarter: cols wn*64 + nb*32
    const int nB = blockIdx.x;          // 256-col block of C (0..1)
    const int bm = blockIdx.y * 128;
    const int bn = nB * 256;
    const int m_ = lane & 31;
    const int q = lane >> 5;

    // ---- A staging map: thread -> (row r0, k-octet o_), one slot each ----
    const int o_ = tid & 3;
    const int r0 = tid >> 2;            // 0..127
    const int sA = (((o_ >> 1) << 2) + (r0 >> 5)) * 512 +
                   ((o_ & 1) * 32 + (r0 & 31)) * 8;
    const float* Ab0 = A + (size_t)(bm + r0) * D1 + o_ * 8;

    // ---- W gload_lds: wave w moves chunks {2w, 2w+1} of each plane ----
    const _Float16* WsrcH = Whi + (size_t)nB * 8192 + (2 * w) * 512 + lane * 8;
    const _Float16* WsrcL = Wlo + (size_t)nB * 8192 + (2 * w) * 512 + lane * 8;
    // per-K-tile stride: 2*16*512 = 16384 halfs

    // ---- fragment read offsets (halfs) ----
    const int fA0 = (wm * 2 + 0) * 512 + lane * 8;   // + ks*2048, +AHo/ALo
    const int fA1 = (wm * 2 + 1) * 512 + lane * 8;
    const int fB0 = (wn * 2 + 0) * 512 + lane * 8;   // + ks*4096, +WHo/WLo
    const int fB1 = (wn * 2 + 1) * 512 + lane * 8;

    floatx16 accm[2][2], accl[2][2];
#pragma unroll
    for (int i = 0; i < 2; ++i)
#pragma unroll
        for (int j = 0; j < 2; ++j) {
            accm[i][j] = (floatx16)0.0f;
            accl[i][j] = (floatx16)0.0f;
        }

    float4 ra0, ra1;   // A prefetch set A
    float4 rb0, rb1;   // A prefetch set B

#define STAGE_A(BUF, F0, F1)                                                   \
    {                                                                          \
        float fv[8] = {F0.x, F0.y, F0.z, F0.w, F1.x, F1.y, F1.z, F1.w};        \
        half8 hh, ll;                                                          \
        _Pragma("unroll")                                                      \
        for (int u = 0; u < 8; ++u) {                                          \
            _Float16 hv = (_Float16)fv[u];                                     \
            hh[u] = hv;                                                        \
            ll[u] = (_Float16)((fv[u] - (float)hv) * 2048.0f);                 \
        }                                                                      \
        *(half8*)&lds[BUF][AHo + sA] = hh;                                     \
        *(half8*)&lds[BUF][ALo + sA] = ll;                                     \
    }

#define MFMA12(BUF, KS)                                                        \
    {                                                                          \
        const half8 ah0 = *(const half8*)&lds[BUF][AHo + fA0 + (KS)*2048];     \
        const half8 ah1 = *(const half8*)&lds[BUF][AHo + fA1 + (KS)*2048];     \
        const half8 al0 = *(const half8*)&lds[BUF][ALo + fA0 + (KS)*2048];     \
        const half8 al1 = *(const half8*)&lds[BUF][ALo + fA1 + (KS)*2048];     \
        const half8 bh0 = *(const half8*)&lds[BUF][WHo + fB0 + (KS)*4096];     \
        const half8 bh1 = *(const half8*)&lds[BUF][WHo + fB1 + (KS)*4096];     \
        const half8 bl0 = *(const half8*)&lds[BUF][WLo + fB0 + (KS)*4096];     \
        const half8 bl1 = *(const half8*)&lds[BUF][WLo + fB1 + (KS)*4096];     \
        accm[0][0] = __builtin_amdgcn_mfma_f32_32x32x16_f16(ah0, bh0, accm[0][0], 0, 0, 0); \
        accm[0][1] = __builtin_amdgcn_mfma_f32_32x32x16_f16(ah0, bh1, accm[0][1], 0, 0, 0); \
        accm[1][0] = __builtin_amdgcn_mfma_f32_32x32x16_f16(ah1, bh0, accm[1][0], 0, 0, 0); \
        accm[1][1] = __builtin_amdgcn_mfma_f32_32x32x16_f16(ah1, bh1, accm[1][1], 0, 0, 0); \
        accl[0][0] = __builtin_amdgcn_mfma_f32_32x32x16_f16(ah0, bl0, accl[0][0], 0, 0, 0); \
        accl[0][1] = __builtin_amdgcn_mfma_f32_32x32x16_f16(ah0, bl1, accl[0][1], 0, 0, 0); \
        accl[1][0] = __builtin_amdgcn_mfma_f32_32x32x16_f16(ah1, bl0, accl[1][0], 0, 0, 0); \
        accl[1][1] = __builtin_amdgcn_mfma_f32_32x32x16_f16(ah1, bl1, accl[1][1], 0, 0, 0); \
        accl[0][0] = __builtin_amdgcn_mfma_f32_32x32x16_f16(al0, bh0, accl[0][0], 0, 0, 0); \
        accl[0][1] = __builtin_amdgcn_mfma_f32_32x32x16_f16(al0, bh1, accl[0][1], 0, 0, 0); \
        accl[1][0] = __builtin_amdgcn_mfma_f32_32x32x16_f16(al1, bh0, accl[1][0], 0, 0, 0); \
        accl[1][1] = __builtin_amdgcn_mfma_f32_32x32x16_f16(al1, bh1, accl[1][1], 0, 0, 0); \
    }

#define BODY(JT, BUF, C0, C1, N0, N1, PREF_A, VMN)                             \
    {                                                                          \
        asm volatile("" ::: "memory"); /* post-barrier fence */                \
        GLOAD16(WsrcH + (size_t)((JT) + 1) * 16384,       &lds[(BUF) ^ 1][WHo + 2 * w * 512]);      \
        GLOAD16(WsrcH + (size_t)((JT) + 1) * 16384 + 512, &lds[(BUF) ^ 1][WHo + (2 * w + 1) * 512]);\
        GLOAD16(WsrcL + (size_t)((JT) + 1) * 16384,       &lds[(BUF) ^ 1][WLo + 2 * w * 512]);      \
        GLOAD16(WsrcL + (size_t)((JT) + 1) * 16384 + 512, &lds[(BUF) ^ 1][WLo + (2 * w + 1) * 512]);\
        __builtin_amdgcn_sched_barrier(0); /* keep gloads before A loads */    \
        if (PREF_A) {                                                          \
            const int kf = ((JT) + 2) * 32;                                    \
            N0 = *(const float4*)(Ab0 + kf);                                   \
            N1 = *(const float4*)(Ab0 + kf + 4);                               \
        }                                                                      \
        STAGE_A((BUF) ^ 1, C0, C1);                                            \
        __builtin_amdgcn_s_setprio(1);                                         \
        MFMA12(BUF, 0);                                                        \
        __builtin_amdgcn_s_setprio(0);                                         \
        __builtin_amdgcn_s_setprio(1);                                         \
        MFMA12(BUF, 1);                                                        \
        __builtin_amdgcn_s_setprio(0);                                         \
        asm volatile("s_waitcnt vmcnt(" #VMN ") lgkmcnt(0)" ::: "memory");     \
        __builtin_amdgcn_s_barrier();                                          \
    }

    // ---- prologue: tile0 staged (from ra), tile1 A-regs (rb) in flight ----
    GLOAD16(WsrcH,       &lds[0][WHo + 2 * w * 512]);
    GLOAD16(WsrcH + 512, &lds[0][WHo + (2 * w + 1) * 512]);
    GLOAD16(WsrcL,       &lds[0][WLo + 2 * w * 512]);
    GLOAD16(WsrcL + 512, &lds[0][WLo + (2 * w + 1) * 512]);
    __builtin_amdgcn_sched_barrier(0);
    ra0 = *(const float4*)(Ab0);
    ra1 = *(const float4*)(Ab0 + 4);
    rb0 = *(const float4*)(Ab0 + 32);
    rb1 = *(const float4*)(Ab0 + 36);
    STAGE_A(0, ra0, ra1);
    asm volatile("s_waitcnt vmcnt(2) lgkmcnt(0)" ::: "memory"); // W0 landed; A1 flies
    __builtin_amdgcn_s_barrier();

    // ---- main loop: tiles 0..29 in buf-parity pairs ----
    // even jj: stage A(jj+1) from rb, prefetch A(jj+2) into ra; odd jj: swap.
    for (int jj = 0; jj < 30; jj += 2) {
        BODY(jj, 0, rb0, rb1, ra0, ra1, 1, 2)
        BODY(jj + 1, 1, ra0, ra1, rb0, rb1, 1, 2)
    }
    // tile 30: stage A(31) from rb, prefetch W(31) only, drain everything
    BODY(30, 0, rb0, rb1, ra0, ra1, 0, 0)
    // tile 31: compute only
    asm volatile("" ::: "memory");
    __builtin_amdgcn_s_setprio(1);
    MFMA12(1, 0);
    __builtin_amdgcn_s_setprio(0);
    __builtin_amdgcn_s_setprio(1);
    MFMA12(1, 1);
    __builtin_amdgcn_s_setprio(0);

#undef BODY
#undef MFMA12
#undef STAGE_A

    // ---- epilogue: C/D layout col=lane&31, row=(reg&3)+8*(reg>>2)+4*q ----
#pragma unroll
    for (int mb = 0; mb < 2; ++mb)
#pragma unroll
        for (int nb = 0; nb < 2; ++nb) {
            const int n = bn + wn * 64 + nb * 32 + m_;
#pragma unroll
            for (int reg = 0; reg < 16; ++reg) {
                const int row = (reg & 3) + 8 * (reg >> 2) + 4 * q;
                const int m = bm + wm * 64 + mb * 32 + row;
                C[(size_t)m * D2 + n] =
                    accm[mb][nb][reg] + accl[mb][nb][reg] * (1.0f / 2048.0f);
            }
        }
}

// ---------------------------------------------------------------------------
// Scan: sequential in t, parallel over (b,d2). Manual 4-deep load pipeline.
// ---------------------------------------------------------------------------
__global__ __launch_bounds__(256) void scan_kernel(float* __restrict__ out) {
    const int j = blockIdx.x * 256 + threadIdx.x;
    float* spk = out;
    float* V = out + TT * SS;
    float* I = out + 2 * TT * SS;

    spk[j] = 0.0f;
    V[j] = 0.0f;
    I[j] = 0.0f;

    float syn = 0.0f, mem = 0.0f;

#define STEP(tt, cc)                                     \
    {                                                    \
        const float reset = (mem > 1.0f) ? 1.0f : 0.0f;  \
        syn = ALPHA * syn + (cc);                        \
        mem = (BETA * mem + syn) * (1.0f - reset);       \
        const int idx = (tt) * SS + j;                   \
        spk[idx] = (mem > 1.0f) ? 1.0f : 0.0f;           \
        V[idx] = mem;                                    \
        I[idx] = syn;                                    \
    }

    float c0 = I[1 * SS + j];
    float c1 = I[2 * SS + j];
    float c2 = I[3 * SS + j];
    float c3 = I[4 * SS + j];

    int t = 1;
    for (; t <= 117; t += 4) {
        const float n0 = I[(t + 4) * SS + j];
        const float n1 = I[(t + 5) * SS + j];
        const float n2 = I[(t + 6) * SS + j];
        const float n3 = I[(t + 7) * SS + j];
        STEP(t + 0, c0);
        STEP(t + 1, c1);
        STEP(t + 2, c2);
        STEP(t + 3, c3);
        c0 = n0; c1 = n1; c2 = n2; c3 = n3;
    }
    {
        const float n0 = I[125 * SS + j];
        const float n1 = I[126 * SS + j];
        const float n2 = I[127 * SS + j];
        STEP(121, c0);
        STEP(122, c1);
        STEP(123, c2);
        STEP(124, c3);
        STEP(125, n0);
        STEP(126, n1);
        STEP(127, n2);
    }
#undef STEP
}

extern "C" void kernel_launch(void* const* d_in, const int* in_sizes, int n_in,
                              void* d_out, int out_size, void* d_ws, size_t ws_size,
                              hipStream_t stream) {
    const float* input = (const float*)d_in[0];   // [128,256,1024]
    const float* weight = (const float*)d_in[1];  // [512,1024]
    float* out = (float*)d_out;

    // f16 hi/lo W planes (pre-swizzled) stashed in spk slices 1..4 (2 MB);
    // gemm reads them, scan overwrites them afterwards.
    _Float16* Whi = (_Float16*)(out + SS);
    _Float16* Wlo = Whi + (size_t)D2 * D1;

    // cur for scan step t at I-region slice t (shift by one slice)
    float* Cdst = out + (size_t)2 * TT * SS + SS;

    convert_w<<<dim3((D2 * D1 / 8) / 256), dim3(256), 0, stream>>>(weight, Whi, Wlo);
    gemm_mfma<<<dim3(2, MM / 128), dim3(512), 0, stream>>>(input, Whi, Wlo, Cdst);
    scan_kernel<<<dim3(SS / 256), dim3(256), 0, stream>>>(out);
}

// Round 4
// 384.788 us; speedup vs baseline: 1.0680x; 1.0067x over previous
//
#include <hip/hip_runtime.h>
#include <cstddef>
#include <cstdint>

// Dims fixed by the reference: input [T=128, B=256, D1=1024] fp32,
// weight [D2=512, D1=1024] fp32. Outputs spk/V/I each [T,B,D2] fp32 concat.
#define TT 128
#define BB 256
#define D1 1024
#define D2 512
#define SS (BB * D2)      // 131072 elems per timestep slice
#define MM (127 * BB)     // 32512 GEMM rows

#define ALPHA 0.8187307530779818f
#define BETA  0.9048374180359595f

typedef _Float16 half8 __attribute__((ext_vector_type(8)));
typedef float floatx16 __attribute__((ext_vector_type(16)));

// ---------------------------------------------------------------------------
// convert_w: fp32 W -> f16 hi + f16 lo*2048 planes, PRE-SWIZZLED into MFMA
// fragment order for the BN=256 GEMM tile (unchanged from round 3).
// Plane layout (halfs): idx = ((kt*2 + nB)*16 + ch)*512 + l*8 + e
//   row = nB*256 + (ch&7)*32 + (l&31); k = kt*32 + (ch>>3)*16 + (l>>5)*8 + e
// ---------------------------------------------------------------------------
__global__ __launch_bounds__(256) void convert_w(const float* __restrict__ W,
                                                 _Float16* __restrict__ Whi,
                                                 _Float16* __restrict__ Wlo) {
    const int T = blockIdx.x * 256 + threadIdx.x;   // 65536 threads, 8 halfs each
    const int l = T & 63;
    const int ch = (T >> 6) & 15;
    const int nB = (T >> 10) & 1;
    const int kt = T >> 11;
    const int row = nB * 256 + (ch & 7) * 32 + (l & 31);
    const int k = kt * 32 + (ch >> 3) * 16 + (l >> 5) * 8;
    const float* src = W + (size_t)row * D1 + k;
    float4 w0 = *(const float4*)src;
    float4 w1 = *(const float4*)(src + 4);
    float f[8] = {w0.x, w0.y, w0.z, w0.w, w1.x, w1.y, w1.z, w1.w};
    half8 hi, lo;
#pragma unroll
    for (int j = 0; j < 8; ++j) {
        _Float16 h = (_Float16)f[j];
        hi[j] = h;
        lo[j] = (_Float16)((f[j] - (float)h) * 2048.0f);
    }
    *(half8*)(Whi + (size_t)T * 8) = hi;
    *(half8*)(Wlo + (size_t)T * 8) = lo;
}

// ---------------------------------------------------------------------------
// Split-f16 MFMA GEMM, 4-phase-per-2-K-tiles schedule (m201-style T3+T4+T5).
// C = (hiA*hiB) + 2^-11 * (hiA*loB + loA*hiB); lo terms pre-scaled by 2048.
//
// Geometry (round 3, kept): BM=128 x BN=256 x BK=32, 512 threads (8 waves,
// 2M x 4N), wave-tile 64x64 as 2x2 of mfma_f32_32x32x16_f16. LDS 2 x 48 KB,
// chunked fragment layout: every ds op is base + lane*16 (conflict-minimal).
//
// Round-4 change: the K-loop is restructured from 1 giant phase per K-tile
// (the ~760 TF 2-phase-structure ceiling, m230/m233) into 4 phases per
// 2 K-tiles. Phase = {VMEM issues / stage  ||  8 ds_reads} -> barrier ->
// lgkmcnt(0) -> setprio(1) 12 MFMA setprio(0) -> [vmcnt cert] -> barrier.
//
// Sync rule: data is CERTIFIED (vmcnt/lgkmcnt before a barrier) at least one
// barrier before the first ds_read that touches it:
//   P0(buf0,KS0): issue 4x W(j+1)->buf1
//   P1(buf0,KS1): stage A(j+1)->buf1 (lgkm+bar certs it), load A(j+2)->ra,
//                 cert vmcnt(2)  [drains W(j+1), keeps 2 A-loads]
//   P2(buf1,KS0): issue 4x W(j+2)->buf0
//   P3(buf1,KS1): stage A(j+2)->buf0, load A(j+3)->rb, cert vmcnt(2)
// Steady-state queue [4W, 2A]; every wait target is >=2 phases old -> no
// stall at any wait point. A-reg consumption waits are compiler-inserted.
// ---------------------------------------------------------------------------
#define AHo 0
#define ALo 4096
#define WHo 8192
#define WLo 16384

#define GLOAD16(gp, lp)                                                        \
    __builtin_amdgcn_global_load_lds(                                          \
        (const __attribute__((address_space(1))) void*)(gp),                   \
        (__attribute__((address_space(3))) void*)(lp), 16, 0, 0)

__global__ __launch_bounds__(512, 2) void gemm_mfma(const float* __restrict__ A,
                                                    const _Float16* __restrict__ Whi,
                                                    const _Float16* __restrict__ Wlo,
                                                    float* __restrict__ C) {
    __shared__ _Float16 lds[2][24576];

    const int tid = threadIdx.x;
    const int lane = tid & 63;
    const int w = tid >> 6;             // wave 0..7
    const int wm = w >> 2;              // M half: rows wm*64 + mb*32
    const int wn = w & 3;               // N quarter: cols wn*64 + nb*32
    const int nB = blockIdx.x;          // 256-col block of C (0..1)
    const int bm = blockIdx.y * 128;
    const int bn = nB * 256;
    const int m_ = lane & 31;
    const int q = lane >> 5;

    // ---- A staging map: thread -> (row r0, k-octet o_), one slot each ----
    const int o_ = tid & 3;
    const int r0 = tid >> 2;            // 0..127
    const int sA = (((o_ >> 1) << 2) + (r0 >> 5)) * 512 +
                   ((o_ & 1) * 32 + (r0 & 31)) * 8;
    const float* Ab0 = A + (size_t)(bm + r0) * D1 + o_ * 8;

    // ---- W gload_lds: wave w moves chunks {2w, 2w+1} of each plane ----
    const _Float16* WsrcH = Whi + (size_t)nB * 8192 + (2 * w) * 512 + lane * 8;
    const _Float16* WsrcL = Wlo + (size_t)nB * 8192 + (2 * w) * 512 + lane * 8;
    // per-K-tile stride: 16384 halfs

    // ---- fragment read offsets (halfs) ----
    const int fA0 = (wm * 2 + 0) * 512 + lane * 8;   // + KS*2048, +AHo/ALo
    const int fA1 = (wm * 2 + 1) * 512 + lane * 8;
    const int fB0 = (wn * 2 + 0) * 512 + lane * 8;   // + KS*4096, +WHo/WLo
    const int fB1 = (wn * 2 + 1) * 512 + lane * 8;

    floatx16 accm[2][2], accl[2][2];
#pragma unroll
    for (int i = 0; i < 2; ++i)
#pragma unroll
        for (int j = 0; j < 2; ++j) {
            accm[i][j] = (floatx16)0.0f;
            accl[i][j] = (floatx16)0.0f;
        }

    float4 ra0, ra1;   // A reg set a
    float4 rb0, rb1;   // A reg set b

#define STAGE_A(BUF, F0, F1)                                                   \
    {                                                                          \
        float fv[8] = {F0.x, F0.y, F0.z, F0.w, F1.x, F1.y, F1.z, F1.w};        \
        half8 hh, ll;                                                          \
        _Pragma("unroll")                                                      \
        for (int u = 0; u < 8; ++u) {                                          \
            _Float16 hv = (_Float16)fv[u];                                     \
            hh[u] = hv;                                                        \
            ll[u] = (_Float16)((fv[u] - (float)hv) * 2048.0f);                 \
        }                                                                      \
        *(half8*)&lds[BUF][AHo + sA] = hh;                                     \
        *(half8*)&lds[BUF][ALo + sA] = ll;                                     \
    }

// One phase: 8 ds_reads from lds[BUF] k-step KS -> bar -> lgkm(0) -> 12 MFMA
// -> optional vmcnt cert -> bar.  DO_W: issue 4 W gloads for K-tile WJT into
// lds[BUF^1].  DO_A: issue 2 A loads for K-tile AJT into N0,N1.  DO_ST:
// stage A from C0,C1 into lds[BUF^1].  CVM: -1 none, else vmcnt(CVM) cert.
#define PHASE(BUF, KS, DO_W, WJT, DO_A, AJT, N0, N1, DO_ST, C0, C1, CVM)       \
    {                                                                          \
        asm volatile("" ::: "memory");                                         \
        if (DO_W) {                                                            \
            GLOAD16(WsrcH + (size_t)(WJT) * 16384,       &lds[(BUF) ^ 1][WHo + 2 * w * 512]);       \
            GLOAD16(WsrcH + (size_t)(WJT) * 16384 + 512, &lds[(BUF) ^ 1][WHo + (2 * w + 1) * 512]); \
            GLOAD16(WsrcL + (size_t)(WJT) * 16384,       &lds[(BUF) ^ 1][WLo + 2 * w * 512]);       \
            GLOAD16(WsrcL + (size_t)(WJT) * 16384 + 512, &lds[(BUF) ^ 1][WLo + (2 * w + 1) * 512]); \
            __builtin_amdgcn_sched_barrier(0);                                 \
        }                                                                      \
        if (DO_A) {                                                            \
            N0 = *(const float4*)(Ab0 + (AJT) * 32);                           \
            N1 = *(const float4*)(Ab0 + (AJT) * 32 + 4);                       \
        }                                                                      \
        if (DO_ST) { STAGE_A((BUF) ^ 1, C0, C1); }                             \
        const half8 ah0 = *(const half8*)&lds[BUF][AHo + fA0 + (KS)*2048];     \
        const half8 ah1 = *(const half8*)&lds[BUF][AHo + fA1 + (KS)*2048];     \
        const half8 al0 = *(const half8*)&lds[BUF][ALo + fA0 + (KS)*2048];     \
        const half8 al1 = *(const half8*)&lds[BUF][ALo + fA1 + (KS)*2048];     \
        const half8 bh0 = *(const half8*)&lds[BUF][WHo + fB0 + (KS)*4096];     \
        const half8 bh1 = *(const half8*)&lds[BUF][WHo + fB1 + (KS)*4096];     \
        const half8 bl0 = *(const half8*)&lds[BUF][WLo + fB0 + (KS)*4096];     \
        const half8 bl1 = *(const half8*)&lds[BUF][WLo + fB1 + (KS)*4096];     \
        __builtin_amdgcn_s_barrier();                                          \
        asm volatile("s_waitcnt lgkmcnt(0)" ::: "memory");                     \
        __builtin_amdgcn_sched_barrier(0);                                     \
        __builtin_amdgcn_s_setprio(1);                                         \
        accm[0][0] = __builtin_amdgcn_mfma_f32_32x32x16_f16(ah0, bh0, accm[0][0], 0, 0, 0); \
        accm[0][1] = __builtin_amdgcn_mfma_f32_32x32x16_f16(ah0, bh1, accm[0][1], 0, 0, 0); \
        accm[1][0] = __builtin_amdgcn_mfma_f32_32x32x16_f16(ah1, bh0, accm[1][0], 0, 0, 0); \
        accm[1][1] = __builtin_amdgcn_mfma_f32_32x32x16_f16(ah1, bh1, accm[1][1], 0, 0, 0); \
        accl[0][0] = __builtin_amdgcn_mfma_f32_32x32x16_f16(ah0, bl0, accl[0][0], 0, 0, 0); \
        accl[0][1] = __builtin_amdgcn_mfma_f32_32x32x16_f16(ah0, bl1, accl[0][1], 0, 0, 0); \
        accl[1][0] = __builtin_amdgcn_mfma_f32_32x32x16_f16(ah1, bl0, accl[1][0], 0, 0, 0); \
        accl[1][1] = __builtin_amdgcn_mfma_f32_32x32x16_f16(ah1, bl1, accl[1][1], 0, 0, 0); \
        accl[0][0] = __builtin_amdgcn_mfma_f32_32x32x16_f16(al0, bh0, accl[0][0], 0, 0, 0); \
        accl[0][1] = __builtin_amdgcn_mfma_f32_32x32x16_f16(al0, bh1, accl[0][1], 0, 0, 0); \
        accl[1][0] = __builtin_amdgcn_mfma_f32_32x32x16_f16(al1, bh0, accl[1][0], 0, 0, 0); \
        accl[1][1] = __builtin_amdgcn_mfma_f32_32x32x16_f16(al1, bh1, accl[1][1], 0, 0, 0); \
        __builtin_amdgcn_s_setprio(0);                                         \
        if ((CVM) == 2) asm volatile("s_waitcnt vmcnt(2)" ::: "memory");       \
        else if ((CVM) == 0) asm volatile("s_waitcnt vmcnt(0)" ::: "memory");  \
        __builtin_amdgcn_s_barrier();                                          \
    }

    // ---- prologue: W(0)->buf0 in flight; A(0)->ra, A(1)->rb; stage A(0) ----
    GLOAD16(WsrcH,       &lds[0][WHo + 2 * w * 512]);
    GLOAD16(WsrcH + 512, &lds[0][WHo + (2 * w + 1) * 512]);
    GLOAD16(WsrcL,       &lds[0][WLo + 2 * w * 512]);
    GLOAD16(WsrcL + 512, &lds[0][WLo + (2 * w + 1) * 512]);
    __builtin_amdgcn_sched_barrier(0);
    ra0 = *(const float4*)(Ab0);
    ra1 = *(const float4*)(Ab0 + 4);
    rb0 = *(const float4*)(Ab0 + 32);
    rb1 = *(const float4*)(Ab0 + 36);
    asm volatile("s_waitcnt vmcnt(2)" ::: "memory");  // W(0)+A(0) landed; A(1) flies
    STAGE_A(0, ra0, ra1);
    asm volatile("s_waitcnt lgkmcnt(0)" ::: "memory");
    __builtin_amdgcn_s_barrier();
    // queue entering main loop: [2x A(1)]

    // ---- main loop: iterations over tile pairs (j, j+1), j = 0,2,...,28 ----
    for (int j = 0; j < 30; j += 2) {
        PHASE(0, 0, 1, j + 1, 0, 0, ra0, ra1, 0, ra0, ra1, -1)       // P0
        PHASE(0, 1, 0, 0, 1, j + 2, ra0, ra1, 1, rb0, rb1, 2)        // P1
        PHASE(1, 0, 1, j + 2, 0, 0, rb0, rb1, 0, rb0, rb1, -1)       // P2
        PHASE(1, 1, 0, 0, 1, j + 3, rb0, rb1, 1, ra0, ra1, 2)        // P3
    }
    // ---- tail: tiles 30, 31 (W(31) issued here; A(31) in rb from j=28 P3) --
    PHASE(0, 0, 1, 31, 0, 0, ra0, ra1, 0, ra0, ra1, -1)              // P0
    PHASE(0, 1, 0, 0, 0, 0, ra0, ra1, 1, rb0, rb1, 0)                // P1: cert vm0
    PHASE(1, 0, 0, 0, 0, 0, ra0, ra1, 0, ra0, ra1, -1)               // P2
    PHASE(1, 1, 0, 0, 0, 0, ra0, ra1, 0, ra0, ra1, -1)               // P3

#undef PHASE
#undef STAGE_A

    // ---- epilogue: C/D layout col=lane&31, row=(reg&3)+8*(reg>>2)+4*q ----
#pragma unroll
    for (int mb = 0; mb < 2; ++mb)
#pragma unroll
        for (int nb = 0; nb < 2; ++nb) {
            const int n = bn + wn * 64 + nb * 32 + m_;
#pragma unroll
            for (int reg = 0; reg < 16; ++reg) {
                const int row = (reg & 3) + 8 * (reg >> 2) + 4 * q;
                const int m = bm + wm * 64 + mb * 32 + row;
                C[(size_t)m * D2 + n] =
                    accm[mb][nb][reg] + accl[mb][nb][reg] * (1.0f / 2048.0f);
            }
        }
}

// ---------------------------------------------------------------------------
// Scan: sequential in t, parallel over (b,d2). 8-deep load pipeline (Little's
// law: 8 waves/CU x 8 x 256 B = 16 KB in flight vs ~22 KB needed at HBM lat).
// ---------------------------------------------------------------------------
__global__ __launch_bounds__(256) void scan_kernel(float* __restrict__ out) {
    const int j = blockIdx.x * 256 + threadIdx.x;
    float* spk = out;
    float* V = out + TT * SS;
    float* I = out + 2 * TT * SS;

    spk[j] = 0.0f;
    V[j] = 0.0f;
    I[j] = 0.0f;

    float syn = 0.0f, mem = 0.0f;

#define STEP(tt, cc)                                     \
    {                                                    \
        const float reset = (mem > 1.0f) ? 1.0f : 0.0f;  \
        syn = ALPHA * syn + (cc);                        \
        mem = (BETA * mem + syn) * (1.0f - reset);       \
        const int idx = (tt) * SS + j;                   \
        spk[idx] = (mem > 1.0f) ? 1.0f : 0.0f;           \
        V[idx] = mem;                                    \
        I[idx] = syn;                                    \
    }

    float c0 = I[1 * SS + j];
    float c1 = I[2 * SS + j];
    float c2 = I[3 * SS + j];
    float c3 = I[4 * SS + j];
    float d0 = I[5 * SS + j];
    float d1 = I[6 * SS + j];
    float d2 = I[7 * SS + j];
    float d3 = I[8 * SS + j];

    int t = 1;
    for (; t <= 113; t += 4) {
        // prefetch 2 groups ahead (8 loads in flight)
        const float n0 = I[(t + 8) * SS + j];
        const float n1 = I[(t + 9) * SS + j];
        const float n2 = I[(t + 10) * SS + j];
        const float n3 = I[(t + 11) * SS + j];
        STEP(t + 0, c0);
        STEP(t + 1, c1);
        STEP(t + 2, c2);
        STEP(t + 3, c3);
        c0 = d0; c1 = d1; c2 = d2; c3 = d3;
        d0 = n0; d1 = n1; d2 = n2; d3 = n3;
    }
    // t == 117: c = I[117..120], d = I[121..124]; remaining 125..127
    {
        const float n0 = I[125 * SS + j];
        const float n1 = I[126 * SS + j];
        const float n2 = I[127 * SS + j];
        STEP(117, c0);
        STEP(118, c1);
        STEP(119, c2);
        STEP(120, c3);
        STEP(121, d0);
        STEP(122, d1);
        STEP(123, d2);
        STEP(124, d3);
        STEP(125, n0);
        STEP(126, n1);
        STEP(127, n2);
    }
#undef STEP
}

extern "C" void kernel_launch(void* const* d_in, const int* in_sizes, int n_in,
                              void* d_out, int out_size, void* d_ws, size_t ws_size,
                              hipStream_t stream) {
    const float* input = (const float*)d_in[0];   // [128,256,1024]
    const float* weight = (const float*)d_in[1];  // [512,1024]
    float* out = (float*)d_out;

    // f16 hi/lo W planes (pre-swizzled) stashed in spk slices 1..4 (2 MB);
    // gemm reads them, scan overwrites them afterwards.
    _Float16* Whi = (_Float16*)(out + SS);
    _Float16* Wlo = Whi + (size_t)D2 * D1;

    // cur for scan step t at I-region slice t (shift by one slice)
    float* Cdst = out + (size_t)2 * TT * SS + SS;

    convert_w<<<dim3((D2 * D1 / 8) / 256), dim3(256), 0, stream>>>(weight, Whi, Wlo);
    gemm_mfma<<<dim3(2, MM / 128), dim3(512), 0, stream>>>(input, Whi, Wlo, Cdst);
    scan_kernel<<<dim3(SS / 256), dim3(256), 0, stream>>>(out);
}